// Round 11
// baseline (326.989 us; speedup 1.0000x reference)
//
#include <hip/hip_runtime.h>

typedef __attribute__((ext_vector_type(8))) short bf16x8;
typedef __attribute__((ext_vector_type(16))) float f32x16;

union FragU { bf16x8 v; unsigned int u[4]; };
struct Wptrs { const float* p[16]; };

#define ROWS 384
#define THREADS 1024

__device__ __forceinline__ unsigned int bfb(float f) {
  unsigned int u = __builtin_bit_cast(unsigned int, f);
  return (u + 0x7fffu + ((u >> 16) & 1u)) >> 16;   // RNE f32 -> bf16 bits
}
__device__ __forceinline__ unsigned int cvtpk(float lo, float hi) {
  unsigned int d;
  asm("v_cvt_pk_bf16_f32 %0, %1, %2" : "=v"(d) : "v"(lo), "v"(hi));
  return d;
}
__device__ __forceinline__ float bf2f(unsigned short b) {
  return __builtin_bit_cast(float, (unsigned int)b << 16);
}
__device__ __forceinline__ float silu_f(float x) {
  float e = __builtin_amdgcn_exp2f(-1.4426950408889634f * x);
  return x * __builtin_amdgcn_rcpf(1.0f + e);
}
__device__ __forceinline__ f32x16 zero16() {
  f32x16 z;
  #pragma unroll
  for (int i = 0; i < 16; ++i) z[i] = 0.0f;
  return z;
}
__device__ __forceinline__ bf16x8 ldA(const unsigned short* __restrict__ wsb, int tile, int l31, int hi, int h) {
  return *(const bf16x8*)(wsb + ((tile * 32 + l31) << 5) + h * 16 + hi * 8);
}

// C layout (32x32x16): col p = lane&31, row j = (reg&3)+8*(reg>>2)+4*hi.
// Next-layer B frags via 4x v_permlane32_swap_b32 (verified R1-R3/R7/R8/R10 network).
__device__ __forceinline__ void transition(const f32x16& acc, bf16x8& b0, bf16x8& b1) {
  unsigned int P[8];
  #pragma unroll
  for (int t = 0; t < 8; ++t)
    P[t] = cvtpk(silu_f(acc[2*t]), silu_f(acc[2*t+1]));
  asm volatile("v_permlane32_swap_b32 %0, %1" : "+v"(P[0]), "+v"(P[2]));
  asm volatile("v_permlane32_swap_b32 %0, %1" : "+v"(P[1]), "+v"(P[3]));
  asm volatile("v_permlane32_swap_b32 %0, %1" : "+v"(P[4]), "+v"(P[6]));
  asm volatile("v_permlane32_swap_b32 %0, %1" : "+v"(P[5]), "+v"(P[7]));
  FragU f0, f1;
  f0.u[0] = P[0]; f0.u[1] = P[1]; f0.u[2] = P[2]; f0.u[3] = P[3];
  f1.u[0] = P[4]; f1.u[1] = P[5]; f1.u[2] = P[6]; f1.u[3] = P[7];
  b0 = f0.v; b1 = f1.v;
}

// R10-verbatim phase: stage this l's slice into s_in (stride 32, pads zeroed
// in the same store), compute (R7/R8 body), store bf16 quads to natural-72-
// stride s_out at column OFF.
template<int NL, int OFF, int TB>
__device__ __forceinline__ void phase(const float* __restrict__ rad,
    const unsigned short* __restrict__ wsb,
    unsigned short* s_in, unsigned short* s_out, const unsigned short* s_pos,
    const int* s_cnt, const int* s_off, const int* s_gpre,
    int base, int vb, int tid)
{
  constexpr int QPR = NL / 4;
  __syncthreads();                       // prev phase done with s_in (sort done)
  // stage-in: coalesced global read, permuted LDS write, pads zero-filled
  for (int j = tid; j < vb * 8; j += THREADS) {
    int i = j >> 3, q = j & 7;
    uint2 w = make_uint2(0u, 0u);
    if (q < QPR) {
      float4 g = *(const float4*)(rad + (long)(base + i) * 72 + OFF + q * 4);
      w = make_uint2(cvtpk(g.x, g.y), cvtpk(g.z, g.w));
    }
    *(uint2*)(s_in + (int)s_pos[i] * 32 + q * 4) = w;
  }
  __syncthreads();

  // compute: species-uniform 32-row groups (R7/R8/R10 verbatim body)
  const int lane = tid & 63, wid = tid >> 6;
  const int l31 = lane & 31, hi = lane >> 5;
  const int Gtot = s_gpre[4];
  for (int g = wid; g < Gtot; g += THREADS / 64) {
    int s = (g >= s_gpre[1]) + (g >= s_gpre[2]) + (g >= s_gpre[3]);
    int gi = g - s_gpre[s];
    int goff = s_off[s] + gi * 32;
    int gcnt = s_cnt[s] - gi * 32; if (gcnt > 32) gcnt = 32;
    int li = l31 < gcnt ? l31 : gcnt - 1;
    int row = goff + li;

    FragU bx0, bx1;
    bx0.v = *(const bf16x8*)(s_in + row * 32 + hi * 8);
    if (NL > 16) bx1.v = *(const bf16x8*)(s_in + row * 32 + 16 + hi * 8);

    f32x16 acc = zero16();
    acc = __builtin_amdgcn_mfma_f32_32x32x16_bf16(ldA(wsb, TB + s, l31, hi, 0), bx0.v, acc, 0, 0, 0);
    if (NL > 16)
      acc = __builtin_amdgcn_mfma_f32_32x32x16_bf16(ldA(wsb, TB + s, l31, hi, 1), bx1.v, acc, 0, 0, 0);
    bf16x8 b0, b1;
    transition(acc, b0, b1);
    acc = zero16();
    acc = __builtin_amdgcn_mfma_f32_32x32x16_bf16(ldA(wsb, TB + 4 + s, l31, hi, 0), b0, acc, 0, 0, 0);
    acc = __builtin_amdgcn_mfma_f32_32x32x16_bf16(ldA(wsb, TB + 4 + s, l31, hi, 1), b1, acc, 0, 0, 0);
    transition(acc, b0, b1);
    acc = zero16();
    acc = __builtin_amdgcn_mfma_f32_32x32x16_bf16(ldA(wsb, TB + 8 + s, l31, hi, 0), b0, acc, 0, 0, 0);
    acc = __builtin_amdgcn_mfma_f32_32x32x16_bf16(ldA(wsb, TB + 8 + s, l31, hi, 1), b1, acc, 0, 0, 0);
    transition(acc, b0, b1);
    acc = zero16();
    acc = __builtin_amdgcn_mfma_f32_32x32x16_bf16(ldA(wsb, TB + 12 + s, l31, hi, 0), b0, acc, 0, 0, 0);
    acc = __builtin_amdgcn_mfma_f32_32x32x16_bf16(ldA(wsb, TB + 12 + s, l31, hi, 1), b1, acc, 0, 0, 0);

    // store: reg quad t -> jo = 8t + 4hi + 0..3 ; natural 72-stride s_out
    if (l31 < gcnt) {
      int obase = (goff + l31) * 72 + OFF;
      #pragma unroll
      for (int t = 0; t < 4; ++t) {
        if (8 * t + 4 * hi + 4 <= NL) {
          *(uint2*)(s_out + obase + 8 * t + 4 * hi) =
              make_uint2(cvtpk(acc[4*t], acc[4*t+1]), cvtpk(acc[4*t+2], acc[4*t+3]));
        }
      }
    }
  }
}

// weights -> bf16 fragment-ready layout in d_ws:
// ws[l][tile 0..15][j 0..31][k 0..31], tile = layer*4 + species, zeros in K/J pads
__global__ void convert_weights_kernel(Wptrs wp, unsigned short* __restrict__ wsb) {
  int idx = blockIdx.x * 256 + threadIdx.x;          // 65536 total
  const int NLs[4] = {24, 20, 16, 12};
  int l = idx >> 14, r = idx & 16383;
  int tile = r >> 10, j = (r >> 5) & 31, k = r & 31;
  int s = tile & 3, layer = tile >> 2;
  int NL = NLs[l];
  const float* w = wp.p[l * 4 + layer];
  float v = 0.0f;
  if (layer == 0)      { if (k < NL) v = w[(s * NL + k) * 32 + j]; }
  else if (layer == 3) { if (j < NL) v = w[(s * 32 + k) * NL + j]; }
  else                 { v = w[(s * 32 + k) * 32 + j]; }
  wsb[idx] = (unsigned short)bfb(v);
}

__global__ __launch_bounds__(THREADS, 8) void RadialBasis_51316269253437_kernel(
    const float* __restrict__ rad, const int* __restrict__ spc,
    const unsigned short* __restrict__ wsb, float* __restrict__ out, int npairs)
{
  // LDS budget (2 blocks/CU needs <= 81920 B):
  // s_in 24576 + s_out 55296 + s_pos 768 + ctrl 68 = 80708 -> fits 2/CU = 32 waves.
  __shared__ unsigned short s_in[ROWS * 32];    // 24 KB, re-staged per phase
  __shared__ unsigned short s_out[ROWS * 72];   // 54 KB, natural row layout
  __shared__ unsigned short s_pos[ROWS];
  __shared__ int s_cnt[4], s_fill[4], s_off[4], s_gpre[5];
  const int tid = threadIdx.x;
  const int base = blockIdx.x * ROWS;
  int vb = npairs - base; if (vb > ROWS) vb = ROWS;

  if (tid < 4) { s_cnt[tid] = 0; s_fill[tid] = 0; }
  __syncthreads();
  int sp = -1;
  if (tid < vb) sp = spc[base + tid];
  if (sp >= 0) atomicAdd(&s_cnt[sp], 1);
  __syncthreads();
  if (tid == 0) {
    int o = 0, gp = 0;
    #pragma unroll
    for (int s4 = 0; s4 < 4; ++s4) {
      s_off[s4] = o; o += s_cnt[s4];
      s_gpre[s4] = gp; gp += (s_cnt[s4] + 31) >> 5;
    }
    s_gpre[4] = gp;
  }
  __syncthreads();
  if (sp >= 0) {
    int pos = s_off[sp] + atomicAdd(&s_fill[sp], 1);
    s_pos[tid] = (unsigned short)pos;
  }
  // each phase begins with __syncthreads() (covers the sort writes above)
  phase<24,  0,  0>(rad, wsb, s_in, s_out, s_pos, s_cnt, s_off, s_gpre, base, vb, tid);
  phase<20, 24, 16>(rad, wsb, s_in, s_out, s_pos, s_cnt, s_off, s_gpre, base, vb, tid);
  phase<16, 44, 32>(rad, wsb, s_in, s_out, s_pos, s_cnt, s_off, s_gpre, base, vb, tid);
  phase<12, 60, 48>(rad, wsb, s_in, s_out, s_pos, s_cnt, s_off, s_gpre, base, vb, tid);
  __syncthreads();

  // single stage-out: permuted LDS read (natural 72-col rows) -> coalesced float4 writes
  for (int j = tid; j < vb * 18; j += THREADS) {
    int i = j / 18, q = j - i * 18;
    uint2 w = *(const uint2*)(s_out + (int)s_pos[i] * 72 + q * 4);
    float4 v = make_float4(bf2f((unsigned short)(w.x & 0xffff)),
                           bf2f((unsigned short)(w.x >> 16)),
                           bf2f((unsigned short)(w.y & 0xffff)),
                           bf2f((unsigned short)(w.y >> 16)));
    *(float4*)(out + (long)(base + i) * 72 + q * 4) = v;
  }
}

extern "C" void kernel_launch(void* const* d_in, const int* in_sizes, int n_in,
                              void* d_out, int out_size, void* d_ws, size_t ws_size,
                              hipStream_t stream) {
  const float* rad = (const float*)d_in[0];
  const int* spc = (const int*)d_in[1];
  Wptrs wp;
  for (int i = 0; i < 16; ++i) wp.p[i] = (const float*)d_in[2 + i];
  float* out = (float*)d_out;
  unsigned short* wsb = (unsigned short*)d_ws;
  int npairs = in_sizes[0] / 72;

  convert_weights_kernel<<<dim3(256), dim3(256), 0, stream>>>(wp, wsb);
  int grid = (npairs + ROWS - 1) / ROWS;
  RadialBasis_51316269253437_kernel<<<dim3(grid), dim3(THREADS), 0, stream>>>(rad, spc, wsb, out, npairs);
}

// Round 13
// 303.187 us; speedup vs baseline: 1.0785x; 1.0785x over previous
//
#include <hip/hip_runtime.h>

typedef __attribute__((ext_vector_type(8))) short bf16x8;
typedef __attribute__((ext_vector_type(16))) float f32x16;

union FragU { bf16x8 v; unsigned int u[4]; };
struct Wptrs { const float* p[16]; };

#define ROWS 192
#define THREADS 512

__device__ __forceinline__ unsigned int bfb(float f) {
  unsigned int u = __builtin_bit_cast(unsigned int, f);
  return (u + 0x7fffu + ((u >> 16) & 1u)) >> 16;   // RNE f32 -> bf16 bits
}
__device__ __forceinline__ unsigned int cvtpk(float lo, float hi) {
  unsigned int d;
  asm("v_cvt_pk_bf16_f32 %0, %1, %2" : "=v"(d) : "v"(lo), "v"(hi));
  return d;
}
__device__ __forceinline__ float bf2f(unsigned short b) {
  return __builtin_bit_cast(float, (unsigned int)b << 16);
}
__device__ __forceinline__ f32x16 zero16() {
  f32x16 z;
  #pragma unroll
  for (int i = 0; i < 16; ++i) z[i] = 0.0f;
  return z;
}
__device__ __forceinline__ bf16x8 ldA(const unsigned short* __restrict__ wsb, int tile, int l31, int hi, int h) {
  return *(const bf16x8*)(wsb + ((tile * 32 + l31) << 5) + h * 16 + hi * 8);
}

// Weight-folded silu (W1 pre-scaled by c = -log2(e), W4 by -ln2; c*(-ln2)=1 so
// W2/W3 unchanged and the composition is exact): acc arrives as a = c*z, and
// the next-layer input is h' = c*silu(z) = a * rcp(1 + exp2(a)).
// Scalar ops only (R10-proven dataflow minus the argument multiply).
// C layout (32x32x16): col p = lane&31, row j = (reg&3)+8*(reg>>2)+4*hi.
// Next-layer B frags via 4x v_permlane32_swap_b32 (verified R1-R10 network).
__device__ __forceinline__ void transition(const f32x16& acc, bf16x8& b0, bf16x8& b1) {
  unsigned int P[8];
  #pragma unroll
  for (int t = 0; t < 8; ++t) {
    float a0 = acc[2*t], a1 = acc[2*t+1];
    float e0 = __builtin_amdgcn_exp2f(a0);
    float e1 = __builtin_amdgcn_exp2f(a1);
    float h0 = a0 * __builtin_amdgcn_rcpf(1.0f + e0);
    float h1 = a1 * __builtin_amdgcn_rcpf(1.0f + e1);
    P[t] = cvtpk(h0, h1);
  }
  asm volatile("v_permlane32_swap_b32 %0, %1" : "+v"(P[0]), "+v"(P[2]));
  asm volatile("v_permlane32_swap_b32 %0, %1" : "+v"(P[1]), "+v"(P[3]));
  asm volatile("v_permlane32_swap_b32 %0, %1" : "+v"(P[4]), "+v"(P[6]));
  asm volatile("v_permlane32_swap_b32 %0, %1" : "+v"(P[5]), "+v"(P[7]));
  FragU f0, f1;
  f0.u[0] = P[0]; f0.u[1] = P[1]; f0.u[2] = P[2]; f0.u[3] = P[3];
  f1.u[0] = P[4]; f1.u[1] = P[5]; f1.u[2] = P[6]; f1.u[3] = P[7];
  b0 = f0.v; b1 = f1.v;
}

// R10-verbatim phase: stage this l's slice into s_in (stride 32, pads zeroed
// in the same store), compute, store bf16 quads to natural-72-stride s_out.
template<int NL, int OFF, int TB>
__device__ __forceinline__ void phase(const float* __restrict__ rad,
    const unsigned short* __restrict__ wsb,
    unsigned short* s_in, unsigned short* s_out, const unsigned short* s_pos,
    const int* s_cnt, const int* s_off, const int* s_gpre,
    int base, int vb, int tid)
{
  constexpr int QPR = NL / 4;
  __syncthreads();                       // prev phase done with s_in (sort done)
  // stage-in: coalesced global read, permuted LDS write, pads zero-filled
  for (int j = tid; j < vb * 8; j += THREADS) {
    int i = j >> 3, q = j & 7;
    uint2 w = make_uint2(0u, 0u);
    if (q < QPR) {
      float4 g = *(const float4*)(rad + (long)(base + i) * 72 + OFF + q * 4);
      w = make_uint2(cvtpk(g.x, g.y), cvtpk(g.z, g.w));
    }
    *(uint2*)(s_in + (int)s_pos[i] * 32 + q * 4) = w;
  }
  __syncthreads();

  // compute: species-uniform 32-row groups (R10 verbatim body, Z hoisted)
  const int lane = tid & 63, wid = tid >> 6;
  const int l31 = lane & 31, hi = lane >> 5;
  const f32x16 Z = zero16();
  const int Gtot = s_gpre[4];
  for (int g = wid; g < Gtot; g += THREADS / 64) {
    int s = (g >= s_gpre[1]) + (g >= s_gpre[2]) + (g >= s_gpre[3]);
    int gi = g - s_gpre[s];
    int goff = s_off[s] + gi * 32;
    int gcnt = s_cnt[s] - gi * 32; if (gcnt > 32) gcnt = 32;
    int li = l31 < gcnt ? l31 : gcnt - 1;
    int row = goff + li;

    FragU bx0, bx1;
    bx0.v = *(const bf16x8*)(s_in + row * 32 + hi * 8);
    if (NL > 16) bx1.v = *(const bf16x8*)(s_in + row * 32 + 16 + hi * 8);

    f32x16 acc;
    acc = __builtin_amdgcn_mfma_f32_32x32x16_bf16(ldA(wsb, TB + s, l31, hi, 0), bx0.v, Z, 0, 0, 0);
    if (NL > 16)
      acc = __builtin_amdgcn_mfma_f32_32x32x16_bf16(ldA(wsb, TB + s, l31, hi, 1), bx1.v, acc, 0, 0, 0);
    bf16x8 b0, b1;
    transition(acc, b0, b1);
    acc = __builtin_amdgcn_mfma_f32_32x32x16_bf16(ldA(wsb, TB + 4 + s, l31, hi, 0), b0, Z, 0, 0, 0);
    acc = __builtin_amdgcn_mfma_f32_32x32x16_bf16(ldA(wsb, TB + 4 + s, l31, hi, 1), b1, acc, 0, 0, 0);
    transition(acc, b0, b1);
    acc = __builtin_amdgcn_mfma_f32_32x32x16_bf16(ldA(wsb, TB + 8 + s, l31, hi, 0), b0, Z, 0, 0, 0);
    acc = __builtin_amdgcn_mfma_f32_32x32x16_bf16(ldA(wsb, TB + 8 + s, l31, hi, 1), b1, acc, 0, 0, 0);
    transition(acc, b0, b1);
    acc = __builtin_amdgcn_mfma_f32_32x32x16_bf16(ldA(wsb, TB + 12 + s, l31, hi, 0), b0, Z, 0, 0, 0);
    acc = __builtin_amdgcn_mfma_f32_32x32x16_bf16(ldA(wsb, TB + 12 + s, l31, hi, 1), b1, acc, 0, 0, 0);

    // store: reg quad t -> jo = 8t + 4hi + 0..3 ; natural 72-stride s_out
    if (l31 < gcnt) {
      int obase = (goff + l31) * 72 + OFF;
      #pragma unroll
      for (int t = 0; t < 4; ++t) {
        if (8 * t + 4 * hi + 4 <= NL) {
          *(uint2*)(s_out + obase + 8 * t + 4 * hi) =
              make_uint2(cvtpk(acc[4*t], acc[4*t+1]), cvtpk(acc[4*t+2], acc[4*t+3]));
        }
      }
    }
  }
}

// weights -> bf16 fragment-ready layout in d_ws, with silu-constant folding:
// layer 0 (W1) scaled by -log2(e); layer 3 (W4) scaled by -ln2; W2/W3 as-is.
// ws[l][tile 0..15][j 0..31][k 0..31], tile = layer*4 + species, zeros in pads.
__global__ void convert_weights_kernel(Wptrs wp, unsigned short* __restrict__ wsb) {
  int idx = blockIdx.x * 256 + threadIdx.x;          // 65536 total
  const int NLs[4] = {24, 20, 16, 12};
  int l = idx >> 14, r = idx & 16383;
  int tile = r >> 10, j = (r >> 5) & 31, k = r & 31;
  int s = tile & 3, layer = tile >> 2;
  int NL = NLs[l];
  const float* w = wp.p[l * 4 + layer];
  float v = 0.0f;
  if (layer == 0)      { if (k < NL) v = w[(s * NL + k) * 32 + j] * -1.4426950408889634f; }
  else if (layer == 3) { if (j < NL) v = w[(s * 32 + k) * NL + j] * -0.6931471805599453f; }
  else                 { v = w[(s * 32 + k) * 32 + j]; }
  wsb[idx] = (unsigned short)bfb(v);
}

__global__ __launch_bounds__(THREADS, 8) void RadialBasis_51316269253437_kernel(
    const float* __restrict__ rad, const int* __restrict__ spc,
    const unsigned short* __restrict__ wsb, float* __restrict__ out, int npairs)
{
  // LDS: s_in 12288 + s_out 27648 + s_pos 384 + ctrl 68 -> 40448 B -> 4 blocks/CU.
  __shared__ unsigned short s_in[ROWS * 32];
  __shared__ unsigned short s_out[ROWS * 72];
  __shared__ unsigned short s_pos[ROWS];
  __shared__ int s_cnt[4], s_fill[4], s_off[4], s_gpre[5];
  const int tid = threadIdx.x;
  const int base = blockIdx.x * ROWS;
  int vb = npairs - base; if (vb > ROWS) vb = ROWS;

  if (tid < 4) { s_cnt[tid] = 0; s_fill[tid] = 0; }
  __syncthreads();
  int sp = -1;
  if (tid < vb) sp = spc[base + tid];
  if (sp >= 0) atomicAdd(&s_cnt[sp], 1);
  __syncthreads();
  if (tid == 0) {
    int o = 0, gp = 0;
    #pragma unroll
    for (int s4 = 0; s4 < 4; ++s4) {
      s_off[s4] = o; o += s_cnt[s4];
      s_gpre[s4] = gp; gp += (s_cnt[s4] + 31) >> 5;
    }
    s_gpre[4] = gp;
  }
  __syncthreads();
  if (sp >= 0) {
    int pos = s_off[sp] + atomicAdd(&s_fill[sp], 1);
    s_pos[tid] = (unsigned short)pos;
  }
  // each phase begins with __syncthreads() (covers the sort writes above)
  phase<24,  0,  0>(rad, wsb, s_in, s_out, s_pos, s_cnt, s_off, s_gpre, base, vb, tid);
  phase<20, 24, 16>(rad, wsb, s_in, s_out, s_pos, s_cnt, s_off, s_gpre, base, vb, tid);
  phase<16, 44, 32>(rad, wsb, s_in, s_out, s_pos, s_cnt, s_off, s_gpre, base, vb, tid);
  phase<12, 60, 48>(rad, wsb, s_in, s_out, s_pos, s_cnt, s_off, s_gpre, base, vb, tid);
  __syncthreads();

  // single stage-out: permuted LDS read (natural 72-col rows) -> coalesced float4 writes
  for (int j = tid; j < vb * 18; j += THREADS) {
    int i = j / 18, q = j - i * 18;
    uint2 w = *(const uint2*)(s_out + (int)s_pos[i] * 72 + q * 4);
    float4 v = make_float4(bf2f((unsigned short)(w.x & 0xffff)),
                           bf2f((unsigned short)(w.x >> 16)),
                           bf2f((unsigned short)(w.y & 0xffff)),
                           bf2f((unsigned short)(w.y >> 16)));
    *(float4*)(out + (long)(base + i) * 72 + q * 4) = v;
  }
}

extern "C" void kernel_launch(void* const* d_in, const int* in_sizes, int n_in,
                              void* d_out, int out_size, void* d_ws, size_t ws_size,
                              hipStream_t stream) {
  const float* rad = (const float*)d_in[0];
  const int* spc = (const int*)d_in[1];
  Wptrs wp;
  for (int i = 0; i < 16; ++i) wp.p[i] = (const float*)d_in[2 + i];
  float* out = (float*)d_out;
  unsigned short* wsb = (unsigned short*)d_ws;
  int npairs = in_sizes[0] / 72;

  convert_weights_kernel<<<dim3(256), dim3(256), 0, stream>>>(wp, wsb);
  int grid = (npairs + ROWS - 1) / ROWS;
  RadialBasis_51316269253437_kernel<<<dim3(grid), dim3(THREADS), 0, stream>>>(rad, spc, wsb, out, npairs);
}